// Round 11
// baseline (179.530 us; speedup 1.0000x reference)
//
#include <hip/hip_runtime.h>
#include <hip/hip_bf16.h>
#include <math.h>

#define D_MODEL 1024
#define C_DIM   128
#define BATCH   4
#define SEQ     2048
#define BS_ROWS (BATCH*SEQ)

typedef float  f32x4 __attribute__((ext_vector_type(4)));
typedef short  s16x8 __attribute__((ext_vector_type(8)));
typedef unsigned short u16;
typedef unsigned short u16x4 __attribute__((ext_vector_type(4)));

__device__ inline u16 f2bf(float f){
    unsigned u = __builtin_bit_cast(unsigned, f);
    u += 0x7FFF + ((u >> 16) & 1);          // round-to-nearest-even
    return (u16)(u >> 16);
}

// async global->LDS, 16B per lane; LDS dest = wave-uniform base + lane*16
__device__ inline void gl_lds16(const u16* g, u16* l){
    __builtin_amdgcn_global_load_lds(
        (const __attribute__((address_space(1))) void*)g,
        (__attribute__((address_space(3))) void*)l,
        16, 0, 0);
}

// counted vmem wait: wait until <= N vmem instrs outstanding (this wave)
template<int N> __device__ inline void wait_vm(){
    if constexpr (N <= 0)       asm volatile("s_waitcnt vmcnt(0)"  ::: "memory");
    else if constexpr (N == 4)  asm volatile("s_waitcnt vmcnt(4)"  ::: "memory");
    else if constexpr (N == 8)  asm volatile("s_waitcnt vmcnt(8)"  ::: "memory");
    else if constexpr (N == 12) asm volatile("s_waitcnt vmcnt(12)" ::: "memory");
    else if constexpr (N == 16) asm volatile("s_waitcnt vmcnt(16)" ::: "memory");
    else if constexpr (N == 24) asm volatile("s_waitcnt vmcnt(24)" ::: "memory");
    else                        asm volatile("s_waitcnt vmcnt(0)"  ::: "memory");
}

// ---------------------------------------------------------------------------
// bf16 MFMA GEMM:  C[M,N] = scale * A[M,K] @ BT[N,K]^T
// BMxBN tile, BK=64, WMxWN wave-grid, DEPTH-deep LDS pipeline:
//   phase(t): stage tile t+DEPTH-1 into buffer (t+DEPTH-1)%DEPTH (constant
//   offsets, hand-unrolled) -> s_waitcnt vmcnt(min(remaining,DEPTH-1)*NL)
//   [retires exactly tile t's loads; up to DEPTH-1 tiles stay in flight]
//   -> raw s_barrier -> MFMA from buffer t%DEPTH -> raw s_barrier.
// Depth-1 tolerance (~1 compute phase ~310cy) << ~950cy staging latency was
// rounds 4-10's 14.5% MfmaUtil wall; DEPTH=4 gives ~3 phases of tolerance.
// Flags: OUT_BF16; MASK (q-path mask); CSKIP (skip above-diagonal); CK
// (causal K-extent); QKF (fused q/k); EXPSUM (P=exp, causal-zero, rowsum
// atomics); RSCALE (divide by rowsum).
// ---------------------------------------------------------------------------
template<int BM, int BN, int WM, int WN, int DEPTH, int OUT_BF16, int MASK,
         int CSKIP, int CK, int QKF, int EXPSUM, int RSCALE>
__launch_bounds__(WM*WN*64)
__global__ void gemm_bt(const u16* __restrict__ Ag, const u16* __restrict__ Bg,
                        const u16* __restrict__ Bg2,
                        void* __restrict__ Cg, void* __restrict__ Cg2,
                        const float* __restrict__ maskp,
                        float* __restrict__ rowsum,
                        int K, int lda, int ldb, int ldc,
                        long sA, long sB, long sC, float scale)
{
    constexpr int W  = WM * WN;
    constexpr int PM = BM / WM, PN = BN / WN;
    constexpr int FM = PM / 16, FN = PN / 16;
    constexpr int CA = BM / 8 / W;          // A chunks (1KB) per wave per stage
    constexpr int CB = BN / 8 / W;
    constexpr int NL = CA + CB;             // gl_lds instrs per wave per stage
    constexpr int ASZ = BM * 64, BSZ = BN * 64;
    __shared__ u16 AsAll[DEPTH * ASZ];
    __shared__ u16 BsAll[DEPTH * BSZ];

    const int mt = blockIdx.x;
    int nt, path = 0;
    if (QKF) { constexpr int NT = C_DIM / BN; path = blockIdx.y / NT; nt = blockIdx.y % NT; }
    else nt = blockIdx.y;
    if (CSKIP && nt * BN >= (mt + 1) * BM) return;   // above causal diagonal
    const u16* Aa = Ag + (long)blockIdx.z * sA;
    const u16* Bb = ((QKF && path) ? Bg2 : Bg) + (long)blockIdx.z * sB;
    const int tid = threadIdx.x, lane = tid & 63, wave = tid >> 6;
    const int wr = wave / WN, wc = wave % WN;
    const int mbase = mt * BM, nbase = nt * BN;
    int Keff = K;
    if (CK) { int ke = (mt + 1) * BM; Keff = ke < K ? ke : K; }
    const int nkt = Keff >> 6;              // >= 2 for every instantiation

    f32x4 acc[FM][FN];
    #pragma unroll
    for (int m = 0; m < FM; ++m)
        #pragma unroll
        for (int n = 0; n < FN; ++n) acc[m][n] = (f32x4){0.f,0.f,0.f,0.f};

    const int sr  = lane >> 3;                 // row within 8-row chunk
    const int sc8 = (lane & 7) ^ sr;           // XOR-swizzled 16B col slot

// stage tile KT into buffer BUF (BUF is a literal -> constant LDS offsets)
#define STAGE(BUF, KT) do {                                                   \
    const int k0_ = (KT) * 64;                                                \
    _Pragma("unroll")                                                         \
    for (int s = 0; s < CA; ++s) {                                            \
        const int c_ = wave * CA + s;                                         \
        const int row_ = c_ * 8 + sr;                                         \
        gl_lds16(Aa + (size_t)(mbase + row_) * lda + k0_ + sc8 * 8,           \
                 &AsAll[(BUF) * ASZ + c_ * 512]);                             \
    }                                                                         \
    _Pragma("unroll")                                                         \
    for (int s = 0; s < CB; ++s) {                                            \
        const int c_ = wave * CB + s;                                         \
        const int row_ = c_ * 8 + sr;                                         \
        gl_lds16(Bb + (size_t)(nbase + row_) * ldb + k0_ + sc8 * 8,           \
                 &BsAll[(BUF) * BSZ + c_ * 512]);                             \
    }                                                                         \
} while (0)

// MFMA over buffer J (literal -> constant LDS offsets)
#define COMPUTE(J) do {                                                       \
    const u16* Ap_ = &AsAll[(J) * ASZ];                                       \
    const u16* Bp_ = &BsAll[(J) * BSZ];                                       \
    _Pragma("unroll")                                                         \
    for (int ks = 0; ks < 2; ++ks) {                                          \
        s16x8 af[FM], bfr[FN];                                                \
        const int k8 = ks * 4 + (lane >> 4);                                  \
        _Pragma("unroll")                                                     \
        for (int m = 0; m < FM; ++m) {                                        \
            const int row_ = wr * PM + m * 16 + (lane & 15);                  \
            af[m] = *(const s16x8*)&Ap_[row_ * 64 + ((k8 ^ (row_ & 7)) << 3)];\
        }                                                                     \
        _Pragma("unroll")                                                     \
        for (int n = 0; n < FN; ++n) {                                        \
            const int row_ = wc * PN + n * 16 + (lane & 15);                  \
            bfr[n] = *(const s16x8*)&Bp_[row_ * 64 + ((k8 ^ (row_ & 7)) << 3)];\
        }                                                                     \
        _Pragma("unroll")                                                     \
        for (int m = 0; m < FM; ++m)                                          \
            _Pragma("unroll")                                                 \
            for (int n = 0; n < FN; ++n)                                      \
                acc[m][n] = __builtin_amdgcn_mfma_f32_16x16x32_bf16(          \
                                af[m], bfr[n], acc[m][n], 0, 0, 0);           \
    }                                                                         \
} while (0)

// one pipeline phase: stage tile tt+DEPTH-1, retire tile tt, compute buf J
#define PHASE(J, TT) do {                                                     \
    const int tt_ = (TT);                                                     \
    if (tt_ + DEPTH - 1 < nkt) STAGE((((J) + DEPTH - 1) % DEPTH), tt_ + DEPTH - 1); \
    const int ah0_ = nkt - 1 - tt_;                                           \
    const int ah_ = ah0_ < DEPTH - 1 ? ah0_ : DEPTH - 1;                      \
    if      (ah_ >= 3) wait_vm<3 * NL>();                                     \
    else if (ah_ == 2) wait_vm<2 * NL>();                                     \
    else if (ah_ == 1) wait_vm<1 * NL>();                                     \
    else               wait_vm<0>();                                          \
    __builtin_amdgcn_s_barrier();                                             \
    COMPUTE(J);                                                               \
    __builtin_amdgcn_s_barrier();                                             \
} while (0)

    // prologue: stage tiles 0..DEPTH-2
    STAGE(0, 0);
    if constexpr (DEPTH >= 3) { if (nkt > 1) STAGE(1, 1); }
    if constexpr (DEPTH >= 4) { if (nkt > 2) STAGE(2, 2); }

    for (int t = 0; t < nkt; t += DEPTH) {
        PHASE(0, t);
        if (t + 1 >= nkt) break;
        PHASE(1, t + 1);
        if constexpr (DEPTH >= 3) {
            if (t + 2 >= nkt) break;
            PHASE(2, t + 2);
        }
        if constexpr (DEPTH >= 4) {
            if (t + 3 >= nkt) break;
            PHASE(3, t + 3);
        }
    }
#undef PHASE
#undef COMPUTE
#undef STAGE

    // epilogue: C/D layout col=lane&15, row=(lane>>4)*4+r (m89-verified)
    const bool kpath = QKF && path;
    void* Cout = kpath ? Cg2 : Cg;
    const int lr = (lane >> 4) * 4, lc = lane & 15;
    float rs[FM][4];
    if (EXPSUM) {
        #pragma unroll
        for (int m = 0; m < FM; ++m)
            #pragma unroll
            for (int r = 0; r < 4; ++r) rs[m][r] = 0.f;
    }
    #pragma unroll
    for (int m = 0; m < FM; ++m) {
        #pragma unroll
        for (int n = 0; n < FN; ++n) {
            const int gr = mbase + wr * PM + m * 16 + lr;
            const int gc = nbase + wc * PN + n * 16 + lc;
            #pragma unroll
            for (int r = 0; r < 4; ++r) {
                float f = acc[m][n][r] * scale;
                if (EXPSUM) {
                    f = (gc <= gr + r) ? __expf(f) : 0.f;   // causal + exp
                    rs[m][r] += f;
                }
                if (RSCALE) f /= rowsum[(long)blockIdx.z * SEQ + gr + r];
                const size_t off = (size_t)(gr + r) * ldc + gc;
                if (MASK) { if (!kpath) f *= maskp[(long)blockIdx.z * sC + off]; }
                if (OUT_BF16) ((u16*)Cout + (long)blockIdx.z * sC)[off] = f2bf(f);
                else          ((float*)Cout + (long)blockIdx.z * sC)[off] = f;
            }
        }
    }
    if (EXPSUM) {
        #pragma unroll
        for (int m = 0; m < FM; ++m) {
            #pragma unroll
            for (int r = 0; r < 4; ++r) {
                float v = rs[m][r];
                v += __shfl_xor(v, 1); v += __shfl_xor(v, 2);
                v += __shfl_xor(v, 4); v += __shfl_xor(v, 8);
                if ((lane & 15) == 0) {
                    const int gr = mbase + wr * PM + m * 16 + lr + r;
                    atomicAdd(rowsum + (long)blockIdx.z * SEQ + gr, v);
                }
            }
        }
    }
}

// ---------------------------------------------------------------------------
// fp32 -> bf16 transpose (32x32 LDS tiles): out[c][r] = in[r][c]
// ---------------------------------------------------------------------------
__launch_bounds__(256)
__global__ void transpose_cvt(const float* __restrict__ in, u16* __restrict__ out,
                              int R, int Cc)
{
    __shared__ float t[32][33];
    const int c0 = blockIdx.x * 32, r0 = blockIdx.y * 32;
    const int tx = threadIdx.x & 31, ty = threadIdx.x >> 5;
    #pragma unroll
    for (int i = 0; i < 32; i += 8) t[ty + i][tx] = in[(size_t)(r0 + ty + i) * Cc + c0 + tx];
    __syncthreads();
    #pragma unroll
    for (int i = 0; i < 32; i += 8) out[(size_t)(c0 + ty + i) * R + r0 + tx] = f2bf(t[tx][ty + i]);
}

// fp32 -> bf16 straight convert (vectorized), n4 = n/4
__launch_bounds__(256)
__global__ void convert_cvt(const float* __restrict__ in, u16* __restrict__ out, int n4)
{
    for (int i = blockIdx.x * 256 + threadIdx.x; i < n4; i += gridDim.x * 256) {
        float4 f = reinterpret_cast<const float4*>(in)[i];
        u16x4 o = { f2bf(f.x), f2bf(f.y), f2bf(f.z), f2bf(f.w) };
        reinterpret_cast<u16x4*>(out)[i] = o;
    }
}

// ---------------------------------------------------------------------------
extern "C" void kernel_launch(void* const* d_in, const int* in_sizes, int n_in,
                              void* d_out, int out_size, void* d_ws, size_t ws_size,
                              hipStream_t stream)
{
    const float* x    = (const float*)d_in[0];
    const float* A    = (const float*)d_in[1];
    const float* Bm   = (const float*)d_in[2];
    const float* ov   = (const float*)d_in[3];
    const float* mask = (const float*)d_in[4];

    // workspace layout: ~70.3 MiB
    char* w = (char*)d_ws;
    u16* xb   = (u16*)w; w += (size_t)BS_ROWS * D_MODEL * 2;   // x bf16 row-major
    u16* AbT  = (u16*)w; w += (size_t)C_DIM * D_MODEL * 2;     // A^T [C][D]
    u16* Bmb  = (u16*)w; w += (size_t)C_DIM * D_MODEL * 2;     // Bmat [C][D]
    u16* ovT  = (u16*)w; w += (size_t)D_MODEL * D_MODEL * 2;   // ov^T [e][d]
    u16* qm   = (u16*)w; w += (size_t)BS_ROWS * C_DIM * 2;     // masked q
    u16* kk   = (u16*)w; w += (size_t)BS_ROWS * C_DIM * 2;     // k
    u16* sc   = (u16*)w; w += (size_t)BATCH * SEQ * SEQ * 2;   // Pu = exp(scores)
    u16* xovT = (u16*)w; w += (size_t)D_MODEL * BS_ROWS * 2;   // (x@ov)^T [e][k]
    float* rowsum = (float*)w; w += (size_t)BS_ROWS * 4;       // softmax denoms

    hipMemsetAsync(rowsum, 0, (size_t)BS_ROWS * 4, stream);

    // prep: converts / transposes
    convert_cvt<<<2048, 256, 0, stream>>>(x, xb, BS_ROWS * D_MODEL / 4);
    convert_cvt<<<128, 256, 0, stream>>>(Bm, Bmb, C_DIM * D_MODEL / 4);
    transpose_cvt<<<dim3(D_MODEL/32, D_MODEL/32, 1), 256, 0, stream>>>(ov, ovT, D_MODEL, D_MODEL);
    transpose_cvt<<<dim3(C_DIM/32, D_MODEL/32, 1), 256, 0, stream>>>(A, AbT, D_MODEL, C_DIM);

    // xovT[e][k] = sum_d ovT[e][d] * xb[k][d]   (M=1024, N=8192, K=1024)
    // 128x128, 4 waves, DEPTH=4 (128 KB LDS) -> 8x64 = 512 blocks
    gemm_bt<128,128,2,2,4, 1,0,0,0,0,0,0><<<dim3(D_MODEL/128, BS_ROWS/128, 1), 256, 0, stream>>>(
        ovT, xb, nullptr, xovT, nullptr, nullptr, nullptr,
        D_MODEL, D_MODEL, D_MODEL, BS_ROWS, 0, 0, 0, 1.0f);

    // fused q & k projection: 64x64 tiles, 4 waves, DEPTH=4 (64 KB) -> 512 blocks
    gemm_bt<64,64,2,2,4, 1,1,0,0,1,0,0><<<dim3(BS_ROWS/64, 4, 1), 256, 0, stream>>>(
        xb, AbT, Bmb, qm, kk, mask, nullptr,
        D_MODEL, D_MODEL, D_MODEL, C_DIM, 0, 0, 0, 1.0f);

    // Pu = exp(qm @ kk^T / D) causal-zeroed (+ rowsum atomics); nkt=2 -> DEPTH=2
    gemm_bt<128,128,2,2,2, 1,0,1,0,0,1,0><<<dim3(SEQ/128, SEQ/128, BATCH), 256, 0, stream>>>(
        qm, kk, nullptr, sc, nullptr, nullptr, rowsum,
        C_DIM, C_DIM, C_DIM, SEQ,
        (long)SEQ * C_DIM, (long)SEQ * C_DIM, (long)SEQ * SEQ, 1.0f / D_MODEL);

    // out = (Pu @ xovT^T) / rowsum   (per batch, causal K-extent, fp32 out)
    // 128x128, 4 waves, DEPTH=4 -> 16x8x4 = 512 blocks
    gemm_bt<128,128,2,2,4, 0,0,0,1,0,0,1><<<dim3(SEQ/128, D_MODEL/128, BATCH), 256, 0, stream>>>(
        sc, xovT, nullptr, d_out, nullptr, nullptr, rowsum,
        SEQ, SEQ, BS_ROWS, D_MODEL,
        (long)SEQ * SEQ, (long)SEQ /*batch col offset in xovT*/, (long)SEQ * D_MODEL, 1.0f);
}

// Round 12
// 113.517 us; speedup vs baseline: 1.5815x; 1.5815x over previous
//
#include <hip/hip_runtime.h>
#include <hip/hip_bf16.h>
#include <math.h>

#define D_MODEL 1024
#define C_DIM   128
#define BATCH   4
#define SEQ     2048
#define BS_ROWS (BATCH*SEQ)

typedef float  f32x4 __attribute__((ext_vector_type(4)));
typedef short  s16x8 __attribute__((ext_vector_type(8)));
typedef unsigned short u16;
typedef unsigned short u16x4 __attribute__((ext_vector_type(4)));

__device__ inline u16 f2bf(float f){
    unsigned u = __builtin_bit_cast(unsigned, f);
    u += 0x7FFF + ((u >> 16) & 1);          // round-to-nearest-even
    return (u16)(u >> 16);
}

// async global->LDS, 16B per lane; LDS dest = wave-uniform base + lane*16
__device__ inline void gl_lds16(const u16* g, u16* l){
    __builtin_amdgcn_global_load_lds(
        (const __attribute__((address_space(1))) void*)g,
        (__attribute__((address_space(3))) void*)l,
        16, 0, 0);
}

// counted vmem wait: wait until <= N vmem instrs outstanding (this wave)
template<int N> __device__ inline void wait_vm(){
    if constexpr (N <= 0)      asm volatile("s_waitcnt vmcnt(0)" ::: "memory");
    else if constexpr (N == 4) asm volatile("s_waitcnt vmcnt(4)" ::: "memory");
    else if constexpr (N == 8) asm volatile("s_waitcnt vmcnt(8)" ::: "memory");
    else                       asm volatile("s_waitcnt vmcnt(0)" ::: "memory");
}

// ---------------------------------------------------------------------------
// bf16 MFMA GEMM:  C[M,N] = scale * A[M,K] @ BT[N,K]^T
// Round-10 structure (best measured): static disjoint double buffers
// (As0/As1/Bs0/Bs1), 2x-unrolled K-loop, counted vmcnt(NL), raw barriers.
// Round-12 additions:
//  * hoisted staging pointers: per-chunk global addresses computed once,
//    advanced by BK*2 bytes per STAGE (kills per-step 64-bit mul chains).
//  * T1 XCD-chunked bijective blockIdx swizzle (1D grid, nwg%8==0):
//    logical = (bid&7)*(nwg/8) + bid>>3; consecutive logical ids share an
//    operand panel -> panel cached once per XCD-L2 instead of 8x.
// ORD=0: mt fastest within chunk (consecutive share B-panel).
// ORD=1: nt fastest within chunk (consecutive share A-panel).
// Flags: OUT_BF16; MASK (q-path mask); CSKIP (skip above-diagonal); CK
// (causal K-extent); QKF (fused q/k); EXPSUM (P=exp, causal-zero, rowsum
// atomics); RSCALE (divide by rowsum).
// ---------------------------------------------------------------------------
template<int BM, int BN, int WM, int WN, int OUT_BF16, int MASK, int CSKIP,
         int CK, int QKF, int EXPSUM, int RSCALE, int ORD>
__launch_bounds__(WM*WN*64)
__global__ void gemm_bt(const u16* __restrict__ Ag, const u16* __restrict__ Bg,
                        const u16* __restrict__ Bg2,
                        void* __restrict__ Cg, void* __restrict__ Cg2,
                        const float* __restrict__ maskp,
                        float* __restrict__ rowsum,
                        int gx, int gy,
                        int K, int lda, int ldb, int ldc,
                        long sA, long sB, long sC, float scale)
{
    constexpr int W  = WM * WN;
    constexpr int PM = BM / WM, PN = BN / WN;
    constexpr int FM = PM / 16, FN = PN / 16;
    constexpr int CA = BM / 8 / W;          // A chunks (1KB) per wave per stage
    constexpr int CB = BN / 8 / W;
    constexpr int NL = CA + CB;             // gl_lds instrs per wave per stage
    constexpr int ASZ = BM * 64, BSZ = BN * 64;
    __shared__ u16 As0[ASZ];
    __shared__ u16 As1[ASZ];
    __shared__ u16 Bs0[BSZ];
    __shared__ u16 Bs1[BSZ];

    // XCD-chunked bijective swizzle (T1): nwg % 8 == 0 for all launches
    const int nwg = gridDim.x;
    const int l   = (blockIdx.x & 7) * (nwg >> 3) + (blockIdx.x >> 3);
    int mt, nt, z, path = 0;
    if (ORD == 0) { mt = l % gx; const int r = l / gx; nt = r % gy; z = r / gy; }
    else          { nt = l % gy; const int r = l / gy; mt = r % gx; z = r / gx; }
    if (QKF) { constexpr int NT = C_DIM / BN; path = nt / NT; nt = nt % NT; }
    if (CSKIP && nt * BN >= (mt + 1) * BM) return;   // above causal diagonal
    const u16* Aa = Ag + (long)z * sA;
    const u16* Bb = ((QKF && path) ? Bg2 : Bg) + (long)z * sB;
    const int tid = threadIdx.x, lane = tid & 63, wave = tid >> 6;
    const int wr = wave / WN, wc = wave % WN;
    const int mbase = mt * BM, nbase = nt * BN;
    int Keff = K;
    if (CK) { int ke = (mt + 1) * BM; Keff = ke < K ? ke : K; }
    const int nkt = Keff >> 6;              // even by construction

    f32x4 acc[FM][FN];
    #pragma unroll
    for (int m = 0; m < FM; ++m)
        #pragma unroll
        for (int n = 0; n < FN; ++n) acc[m][n] = (f32x4){0.f,0.f,0.f,0.f};

    const int sr  = lane >> 3;                 // row within 8-row chunk
    const int sc8 = (lane & 7) ^ sr;           // XOR-swizzled 16B col slot

    // hoisted staging pointers: one per chunk, advanced 64 elts per STAGE
    const u16* aptr[CA];
    const u16* bptr[CB];
    #pragma unroll
    for (int s = 0; s < CA; ++s) {
        const int c = wave * CA + s;
        aptr[s] = Aa + (size_t)(mbase + c * 8 + sr) * lda + sc8 * 8;
    }
    #pragma unroll
    for (int s = 0; s < CB; ++s) {
        const int c = wave * CB + s;
        bptr[s] = Bb + (size_t)(nbase + c * 8 + sr) * ldb + sc8 * 8;
    }

    auto STAGE = [&](u16 (&Ad)[ASZ], u16 (&Bd)[BSZ]) {
        #pragma unroll
        for (int s = 0; s < CA; ++s) {
            gl_lds16(aptr[s], &Ad[(wave * CA + s) * 512]);
            aptr[s] += 64;
        }
        #pragma unroll
        for (int s = 0; s < CB; ++s) {
            gl_lds16(bptr[s], &Bd[(wave * CB + s) * 512]);
            bptr[s] += 64;
        }
    };

    auto COMPUTE = [&](const u16 (&Ap)[ASZ], const u16 (&Bp)[BSZ]) {
        #pragma unroll
        for (int ks = 0; ks < 2; ++ks) {
            s16x8 af[FM], bfr[FN];
            const int k8 = ks * 4 + (lane >> 4);
            #pragma unroll
            for (int m = 0; m < FM; ++m) {
                const int row = wr * PM + m * 16 + (lane & 15);
                af[m] = *(const s16x8*)&Ap[row * 64 + ((k8 ^ (row & 7)) << 3)];
            }
            #pragma unroll
            for (int n = 0; n < FN; ++n) {
                const int row = wc * PN + n * 16 + (lane & 15);
                bfr[n] = *(const s16x8*)&Bp[row * 64 + ((k8 ^ (row & 7)) << 3)];
            }
            #pragma unroll
            for (int m = 0; m < FM; ++m)
                #pragma unroll
                for (int n = 0; n < FN; ++n)
                    acc[m][n] = __builtin_amdgcn_mfma_f32_16x16x32_bf16(af[m], bfr[n], acc[m][n], 0, 0, 0);
        }
    };

    // prologue: tile 0 into buf0
    STAGE(As0, Bs0);
    for (int t = 0; t < nkt; t += 2) {
        // ---- phase A: compute tile t from buf0; prefetch t+1 into buf1 ----
        STAGE(As1, Bs1);                 // t+1 < nkt always (nkt even)
        wait_vm<NL>();                   // retire tile t's loads only
        __builtin_amdgcn_s_barrier();    // buf0 complete for all waves
        COMPUTE(As0, Bs0);
        __builtin_amdgcn_s_barrier();    // all waves done reading buf0
        // ---- phase B: compute tile t+1 from buf1; prefetch t+2 into buf0 ----
        if (t + 2 < nkt) { STAGE(As0, Bs0); wait_vm<NL>(); }
        else             { wait_vm<0>(); }
        __builtin_amdgcn_s_barrier();    // buf1 complete
        COMPUTE(As1, Bs1);
        __builtin_amdgcn_s_barrier();    // all waves done reading buf1
    }

    // epilogue: C/D layout col=lane&15, row=(lane>>4)*4+r (m89-verified)
    const bool kpath = QKF && path;
    void* Cout = kpath ? Cg2 : Cg;
    const int lr = (lane >> 4) * 4, lc = lane & 15;
    float rs[FM][4];
    if (EXPSUM) {
        #pragma unroll
        for (int m = 0; m < FM; ++m)
            #pragma unroll
            for (int r = 0; r < 4; ++r) rs[m][r] = 0.f;
    }
    #pragma unroll
    for (int m = 0; m < FM; ++m) {
        #pragma unroll
        for (int n = 0; n < FN; ++n) {
            const int gr = mbase + wr * PM + m * 16 + lr;
            const int gc = nbase + wc * PN + n * 16 + lc;
            #pragma unroll
            for (int r = 0; r < 4; ++r) {
                float f = acc[m][n][r] * scale;
                if (EXPSUM) {
                    f = (gc <= gr + r) ? __expf(f) : 0.f;   // causal + exp
                    rs[m][r] += f;
                }
                if (RSCALE) f /= rowsum[(long)z * SEQ + gr + r];
                const size_t off = (size_t)(gr + r) * ldc + gc;
                if (MASK) { if (!kpath) f *= maskp[(long)z * sC + off]; }
                if (OUT_BF16) ((u16*)Cout + (long)z * sC)[off] = f2bf(f);
                else          ((float*)Cout + (long)z * sC)[off] = f;
            }
        }
    }
    if (EXPSUM) {
        #pragma unroll
        for (int m = 0; m < FM; ++m) {
            #pragma unroll
            for (int r = 0; r < 4; ++r) {
                float v = rs[m][r];
                v += __shfl_xor(v, 1); v += __shfl_xor(v, 2);
                v += __shfl_xor(v, 4); v += __shfl_xor(v, 8);
                if ((lane & 15) == 0) {
                    const int gr = mbase + wr * PM + m * 16 + lr + r;
                    atomicAdd(rowsum + (long)z * SEQ + gr, v);
                }
            }
        }
    }
}

// ---------------------------------------------------------------------------
// fp32 -> bf16 transpose (32x32 LDS tiles): out[c][r] = in[r][c]
// ---------------------------------------------------------------------------
__launch_bounds__(256)
__global__ void transpose_cvt(const float* __restrict__ in, u16* __restrict__ out,
                              int R, int Cc)
{
    __shared__ float t[32][33];
    const int c0 = blockIdx.x * 32, r0 = blockIdx.y * 32;
    const int tx = threadIdx.x & 31, ty = threadIdx.x >> 5;
    #pragma unroll
    for (int i = 0; i < 32; i += 8) t[ty + i][tx] = in[(size_t)(r0 + ty + i) * Cc + c0 + tx];
    __syncthreads();
    #pragma unroll
    for (int i = 0; i < 32; i += 8) out[(size_t)(c0 + ty + i) * R + r0 + tx] = f2bf(t[tx][ty + i]);
}

// fp32 -> bf16 straight convert (vectorized), n4 = n/4
__launch_bounds__(256)
__global__ void convert_cvt(const float* __restrict__ in, u16* __restrict__ out, int n4)
{
    for (int i = blockIdx.x * 256 + threadIdx.x; i < n4; i += gridDim.x * 256) {
        float4 f = reinterpret_cast<const float4*>(in)[i];
        u16x4 o = { f2bf(f.x), f2bf(f.y), f2bf(f.z), f2bf(f.w) };
        reinterpret_cast<u16x4*>(out)[i] = o;
    }
}

// ---------------------------------------------------------------------------
extern "C" void kernel_launch(void* const* d_in, const int* in_sizes, int n_in,
                              void* d_out, int out_size, void* d_ws, size_t ws_size,
                              hipStream_t stream)
{
    const float* x    = (const float*)d_in[0];
    const float* A    = (const float*)d_in[1];
    const float* Bm   = (const float*)d_in[2];
    const float* ov   = (const float*)d_in[3];
    const float* mask = (const float*)d_in[4];

    // workspace layout: ~70.3 MiB
    char* w = (char*)d_ws;
    u16* xb   = (u16*)w; w += (size_t)BS_ROWS * D_MODEL * 2;   // x bf16 row-major
    u16* AbT  = (u16*)w; w += (size_t)C_DIM * D_MODEL * 2;     // A^T [C][D]
    u16* Bmb  = (u16*)w; w += (size_t)C_DIM * D_MODEL * 2;     // Bmat [C][D]
    u16* ovT  = (u16*)w; w += (size_t)D_MODEL * D_MODEL * 2;   // ov^T [e][d]
    u16* qm   = (u16*)w; w += (size_t)BS_ROWS * C_DIM * 2;     // masked q
    u16* kk   = (u16*)w; w += (size_t)BS_ROWS * C_DIM * 2;     // k
    u16* sc   = (u16*)w; w += (size_t)BATCH * SEQ * SEQ * 2;   // Pu = exp(scores)
    u16* xovT = (u16*)w; w += (size_t)D_MODEL * BS_ROWS * 2;   // (x@ov)^T [e][k]
    float* rowsum = (float*)w; w += (size_t)BS_ROWS * 4;       // softmax denoms

    hipMemsetAsync(rowsum, 0, (size_t)BS_ROWS * 4, stream);

    // prep: converts / transposes
    convert_cvt<<<2048, 256, 0, stream>>>(x, xb, BS_ROWS * D_MODEL / 4);
    convert_cvt<<<128, 256, 0, stream>>>(Bm, Bmb, C_DIM * D_MODEL / 4);
    transpose_cvt<<<dim3(D_MODEL/32, D_MODEL/32, 1), 256, 0, stream>>>(ov, ovT, D_MODEL, D_MODEL);
    transpose_cvt<<<dim3(C_DIM/32, D_MODEL/32, 1), 256, 0, stream>>>(A, AbT, D_MODEL, C_DIM);

    // xovT[e][k] = sum_d ovT[e][d] * xb[k][d]   (M=1024, N=8192, K=1024)
    // 128x128, 4 waves; 512 blocks; ORD=0 (8 consecutive share xb panel)
    gemm_bt<128,128,2,2, 1,0,0,0,0,0,0, 0><<<512, 256, 0, stream>>>(
        ovT, xb, nullptr, xovT, nullptr, nullptr, nullptr,
        /*gx*/8, /*gy*/64,
        D_MODEL, D_MODEL, D_MODEL, BS_ROWS, 0, 0, 0, 1.0f);

    // fused q & k projection: 64x64 tiles, 4 waves; 512 blocks; ORD=1
    // (4 consecutive y-variants share the xb A-panel)
    gemm_bt<64,64,2,2, 1,1,0,0,1,0,0, 1><<<512, 256, 0, stream>>>(
        xb, AbT, Bmb, qm, kk, mask, nullptr,
        /*gx*/128, /*gy*/4,
        D_MODEL, D_MODEL, D_MODEL, C_DIM, 0, 0, 0, 1.0f);

    // Pu = exp(qm @ kk^T / D) causal-zeroed (+ rowsum atomics); 1024 blocks
    // ORD=1: 16 consecutive share the qm A-panel (same batch,mt)
    gemm_bt<128,128,2,2, 1,0,1,0,0,1,0, 1><<<1024, 256, 0, stream>>>(
        qm, kk, nullptr, sc, nullptr, nullptr, rowsum,
        /*gx*/16, /*gy*/16,
        C_DIM, C_DIM, C_DIM, SEQ,
        (long)SEQ * C_DIM, (long)SEQ * C_DIM, (long)SEQ * SEQ, 1.0f / D_MODEL);

    // out = (Pu @ xovT^T) / rowsum   (per batch, causal K-extent, fp32 out)
    // 128x128, 4 waves; 512 blocks; ORD=0 (16 consecutive share xovT B-panel)
    gemm_bt<128,128,2,2, 0,0,0,1,0,0,1, 0><<<512, 256, 0, stream>>>(
        sc, xovT, nullptr, d_out, nullptr, nullptr, rowsum,
        /*gx*/16, /*gy*/8,
        SEQ, SEQ, BS_ROWS, D_MODEL,
        (long)SEQ * SEQ, (long)SEQ /*batch col offset in xovT*/, (long)SEQ * D_MODEL, 1.0f);
}